// Round 2
// baseline (566.353 us; speedup 1.0000x reference)
//
#include <hip/hip_runtime.h>
#include <math.h>

// VGAE Encoder: GCNConv(2->64)+ReLU -> {GCNConv(64->16) mu, GCNConv(64->16) logstd}
// CSR-by-dst counting sort, then gather-side (atomic-free) aggregation.

#define HID 64
#define OUTC 16

// ---------- CSR build ----------
__global__ void k_count(const int* __restrict__ dst, int* __restrict__ count, int E) {
    int i = blockIdx.x * blockDim.x + threadIdx.x;
    int stride = gridDim.x * blockDim.x;
    for (; i < E; i += stride) atomicAdd(&count[dst[i]], 1);
}

__global__ void k_chunksum(const int* __restrict__ count, int* __restrict__ chunk_sum, int N) {
    int c = blockIdx.x;
    int base = c * 1024;
    int sum = 0;
    for (int t = threadIdx.x; t < 1024; t += 256) {
        int i = base + t;
        if (i < N) sum += count[i];
    }
    __shared__ int sm[256];
    sm[threadIdx.x] = sum;
    __syncthreads();
    for (int off = 128; off > 0; off >>= 1) {
        if (threadIdx.x < off) sm[threadIdx.x] += sm[threadIdx.x + off];
        __syncthreads();
    }
    if (threadIdx.x == 0) chunk_sum[c] = sm[0];
}

// single block, 128 threads; NCHUNK <= 128
__global__ void k_chunkscan(const int* __restrict__ chunk_sum, int* __restrict__ chunk_base,
                            int* __restrict__ row_ptr, int nchunk, int N) {
    __shared__ int sm[128];
    int tid = threadIdx.x;
    int v = (tid < nchunk) ? chunk_sum[tid] : 0;
    sm[tid] = v;
    __syncthreads();
    for (int off = 1; off < 128; off <<= 1) {
        int a = (tid >= off) ? sm[tid - off] : 0;
        __syncthreads();
        sm[tid] += a;
        __syncthreads();
    }
    int incl = sm[tid];
    if (tid < nchunk) chunk_base[tid] = incl - v;  // exclusive
    if (tid == 127) row_ptr[N] = sm[127];          // total = E
}

__global__ void k_nodescan(const int* __restrict__ count, const int* __restrict__ chunk_base,
                           int* __restrict__ row_ptr, int* __restrict__ cursor,
                           float* __restrict__ dis, int N) {
    __shared__ int sm[1024];
    int c = blockIdx.x;
    int tid = threadIdx.x;
    int i = c * 1024 + tid;
    int v = (i < N) ? count[i] : 0;
    sm[tid] = v;
    __syncthreads();
    for (int off = 1; off < 1024; off <<= 1) {
        int a = (tid >= off) ? sm[tid - off] : 0;
        __syncthreads();
        sm[tid] += a;
        __syncthreads();
    }
    if (i < N) {
        int excl = chunk_base[c] + sm[tid] - v;
        row_ptr[i] = excl;
        cursor[i]  = excl;
        dis[i] = rsqrtf(1.0f + (float)v);
    }
}

__global__ void k_scatter(const int* __restrict__ src, const int* __restrict__ dst,
                          int* __restrict__ cursor, int* __restrict__ sorted_src, int E) {
    int i = blockIdx.x * blockDim.x + threadIdx.x;
    int stride = gridDim.x * blockDim.x;
    for (; i < E; i += stride) {
        int d = dst[i];
        int p = atomicAdd(&cursor[d], 1);
        sorted_src[p] = src[i];
    }
}

// ---------- layer 1 ----------
// h_lin[i][j] = x[i][0]*W1[0][j] + x[i][1]*W1[1][j]
__global__ void k_hlin(const float* __restrict__ x, const float* __restrict__ W1,
                       float* __restrict__ h_lin, int N) {
    int t = blockIdx.x * blockDim.x + threadIdx.x;
    int stride = gridDim.x * blockDim.x;
    for (; t < N * HID; t += stride) {
        int i = t >> 6, j = t & 63;
        h_lin[t] = x[2 * i] * W1[j] + x[2 * i + 1] * W1[HID + j];
    }
}

// one wave (64 lanes = 64 channels) per node
__global__ void k_agg1(const float* __restrict__ h_lin, const int* __restrict__ row_ptr,
                       const int* __restrict__ sorted_src, const float* __restrict__ dis,
                       const float* __restrict__ b1, float* __restrict__ h, int N) {
    int wpb = blockDim.x >> 6;
    int node = blockIdx.x * wpb + (threadIdx.x >> 6);
    int nstride = gridDim.x * wpb;
    int j = threadIdx.x & 63;
    for (; node < N; node += nstride) {
        float di = dis[node];
        float acc = di * di * h_lin[node * HID + j];
        int beg = row_ptr[node], end = row_ptr[node + 1];
        for (int k = beg; k < end; ++k) {
            int s = sorted_src[k];
            acc = fmaf(dis[s] * di, h_lin[s * HID + j], acc);
        }
        acc += b1[j];
        h[node * HID + j] = fmaxf(acc, 0.0f);
    }
}

// ---------- layer 2 projection: hml[n][c] = sum_k h[n][k]*Wc[k][c], c<16 mu else logstd ----------
__global__ void k_proj(const float* __restrict__ h, const float* __restrict__ W_mu,
                       const float* __restrict__ W_logstd, float* __restrict__ hml, int N) {
    __shared__ float Wc[HID * 32];
    for (int t = threadIdx.x; t < HID * 32; t += blockDim.x) {
        int k = t >> 5, c = t & 31;
        Wc[t] = (c < OUTC) ? W_mu[k * OUTC + c] : W_logstd[k * OUTC + (c - OUTC)];
    }
    __syncthreads();
    int wpb = blockDim.x >> 5;
    int node = blockIdx.x * wpb + (threadIdx.x >> 5);
    int nstride = gridDim.x * wpb;
    int c = threadIdx.x & 31;
    for (; node < N; node += nstride) {
        const float* hp = h + node * HID;
        float acc = 0.0f;
#pragma unroll
        for (int k = 0; k < HID; ++k) acc = fmaf(hp[k], Wc[k * 32 + c], acc);
        hml[node * 32 + c] = acc;
    }
}

// ---------- layer 2 aggregation: 32 lanes per node (16 mu + 16 logstd) ----------
__global__ void k_agg2(const float* __restrict__ hml, const int* __restrict__ row_ptr,
                       const int* __restrict__ sorted_src, const float* __restrict__ dis,
                       const float* __restrict__ b_mu, const float* __restrict__ b_logstd,
                       float* __restrict__ out, int N) {
    int wpb = blockDim.x >> 5;
    int node = blockIdx.x * wpb + (threadIdx.x >> 5);
    int nstride = gridDim.x * wpb;
    int c = threadIdx.x & 31;
    for (; node < N; node += nstride) {
        float di = dis[node];
        float acc = di * di * hml[node * 32 + c];
        int beg = row_ptr[node], end = row_ptr[node + 1];
        for (int k = beg; k < end; ++k) {
            int s = sorted_src[k];
            acc = fmaf(dis[s] * di, hml[s * 32 + c], acc);
        }
        int idx;
        float v;
        if (c < OUTC) {
            v = acc + b_mu[c];
            idx = node * OUTC + c;
        } else {
            v = acc + b_logstd[c - OUTC];
            idx = (N + node) * OUTC + (c - OUTC);
        }
        out[idx] = v;
    }
}

extern "C" void kernel_launch(void* const* d_in, const int* in_sizes, int n_in,
                              void* d_out, int out_size, void* d_ws, size_t ws_size,
                              hipStream_t stream) {
    const float* x        = (const float*)d_in[0];
    const int*   eidx     = (const int*)d_in[1];
    const float* W1       = (const float*)d_in[2];
    const float* b1       = (const float*)d_in[3];
    const float* W_mu     = (const float*)d_in[4];
    const float* b_mu     = (const float*)d_in[5];
    const float* W_logstd = (const float*)d_in[6];
    const float* b_logstd = (const float*)d_in[7];
    float* out = (float*)d_out;

    const int N = in_sizes[0] / 2;       // 100000
    const int E = in_sizes[1] / 2;       // 1600000
    const int NCHUNK = (N + 1023) / 1024;

    const int* src = eidx;
    const int* dst = eidx + E;

    // workspace layout (256B-aligned segments)
    char* w = (char*)d_ws;
    auto alloc = [&](size_t bytes) -> void* {
        void* p = (void*)w;
        w += (bytes + 255) & ~(size_t)255;
        return p;
    };
    float* dis        = (float*)alloc((size_t)N * 4);
    int*   count      = (int*)  alloc((size_t)N * 4);
    int*   row_ptr    = (int*)  alloc((size_t)(N + 1) * 4);
    int*   cursor     = (int*)  alloc((size_t)N * 4);
    int*   chunk_sum  = (int*)  alloc((size_t)NCHUNK * 4);
    int*   chunk_base = (int*)  alloc((size_t)NCHUNK * 4);
    int*   sorted_src = (int*)  alloc((size_t)E * 4);
    float* h_lin      = (float*)alloc((size_t)N * HID * 4);
    float* h          = (float*)alloc((size_t)N * HID * 4);
    float* hml        = (float*)alloc((size_t)N * 32 * 4);

    hipMemsetAsync(count, 0, (size_t)N * sizeof(int), stream);

    k_count   <<<2048, 256, 0, stream>>>(dst, count, E);
    k_chunksum<<<NCHUNK, 256, 0, stream>>>(count, chunk_sum, N);
    k_chunkscan<<<1, 128, 0, stream>>>(chunk_sum, chunk_base, row_ptr, NCHUNK, N);
    k_nodescan<<<NCHUNK, 1024, 0, stream>>>(count, chunk_base, row_ptr, cursor, dis, N);
    k_scatter <<<2048, 256, 0, stream>>>(src, dst, cursor, sorted_src, E);
    k_hlin    <<<2048, 256, 0, stream>>>(x, W1, h_lin, N);
    k_agg1    <<<(N + 3) / 4, 256, 0, stream>>>(h_lin, row_ptr, sorted_src, dis, b1, h, N);
    k_proj    <<<(N + 7) / 8, 256, 0, stream>>>(h, W_mu, W_logstd, hml, N);
    k_agg2    <<<(N + 7) / 8, 256, 0, stream>>>(hml, row_ptr, sorted_src, dis, b_mu, b_logstd, out, N);
}

// Round 3
// 439.903 us; speedup vs baseline: 1.2875x; 1.2875x over previous
//
#include <hip/hip_runtime.h>
#include <math.h>

// VGAE Encoder: GCNConv(2->64)+ReLU -> {GCNConv(64->16) mu, GCNConv(64->16) logstd}
// Key identity: A_norm(X W1) = (A_norm X) W1 -> aggregate 2-channel X (8B/edge)
// instead of 64-channel h_lin (256B/edge). Layer 2 projects first (32ch) then
// aggregates 128B/edge via CSR gather.

#define HID 64
#define OUTC 16

// ---------- CSR build ----------
__global__ void k_count(const int* __restrict__ dst, int* __restrict__ count, int E) {
    int i = blockIdx.x * blockDim.x + threadIdx.x;
    int stride = gridDim.x * blockDim.x;
    for (; i < E; i += stride) atomicAdd(&count[dst[i]], 1);
}

__global__ void k_chunksum(const int* __restrict__ count, int* __restrict__ chunk_sum, int N) {
    int c = blockIdx.x;
    int base = c * 1024;
    int sum = 0;
    for (int t = threadIdx.x; t < 1024; t += 256) {
        int i = base + t;
        if (i < N) sum += count[i];
    }
    __shared__ int sm[256];
    sm[threadIdx.x] = sum;
    __syncthreads();
    for (int off = 128; off > 0; off >>= 1) {
        if (threadIdx.x < off) sm[threadIdx.x] += sm[threadIdx.x + off];
        __syncthreads();
    }
    if (threadIdx.x == 0) chunk_sum[c] = sm[0];
}

// single block, 128 threads; NCHUNK <= 128
__global__ void k_chunkscan(const int* __restrict__ chunk_sum, int* __restrict__ chunk_base,
                            int* __restrict__ row_ptr, int nchunk, int N) {
    __shared__ int sm[128];
    int tid = threadIdx.x;
    int v = (tid < nchunk) ? chunk_sum[tid] : 0;
    sm[tid] = v;
    __syncthreads();
    for (int off = 1; off < 128; off <<= 1) {
        int a = (tid >= off) ? sm[tid - off] : 0;
        __syncthreads();
        sm[tid] += a;
        __syncthreads();
    }
    int incl = sm[tid];
    if (tid < nchunk) chunk_base[tid] = incl - v;  // exclusive
    if (tid == 127) row_ptr[N] = sm[127];          // total = E
}

// per-node: exclusive scan -> row_ptr/cursor; dis = rsqrt(1+deg);
// seed ax with the self-loop term dis^2 * x[i]
__global__ void k_nodescan(const int* __restrict__ count, const int* __restrict__ chunk_base,
                           const float* __restrict__ x,
                           int* __restrict__ row_ptr, int* __restrict__ cursor,
                           float* __restrict__ dis, float* __restrict__ ax, int N) {
    __shared__ int sm[1024];
    int c = blockIdx.x;
    int tid = threadIdx.x;
    int i = c * 1024 + tid;
    int v = (i < N) ? count[i] : 0;
    sm[tid] = v;
    __syncthreads();
    for (int off = 1; off < 1024; off <<= 1) {
        int a = (tid >= off) ? sm[tid - off] : 0;
        __syncthreads();
        sm[tid] += a;
        __syncthreads();
    }
    if (i < N) {
        int excl = chunk_base[c] + sm[tid] - v;
        row_ptr[i] = excl;
        cursor[i]  = excl;
        float di = rsqrtf(1.0f + (float)v);
        dis[i] = di;
        float2 xv = ((const float2*)x)[i];
        ((float2*)ax)[i] = make_float2(di * di * xv.x, di * di * xv.y);
    }
}

// scatter edges into CSR order AND scatter-aggregate the 2-channel x
__global__ void k_scatter_agg(const int* __restrict__ src, const int* __restrict__ dst,
                              const float* __restrict__ x, const float* __restrict__ dis,
                              int* __restrict__ cursor, int* __restrict__ sorted_src,
                              float* __restrict__ ax, int E) {
    int i = blockIdx.x * blockDim.x + threadIdx.x;
    int stride = gridDim.x * blockDim.x;
    for (; i < E; i += stride) {
        int d = dst[i];
        int s = src[i];
        int p = atomicAdd(&cursor[d], 1);
        sorted_src[p] = s;
        float w = dis[s] * dis[d];
        float2 xv = ((const float2*)x)[s];
        atomicAdd(&ax[2 * d + 0], w * xv.x);
        atomicAdd(&ax[2 * d + 1], w * xv.y);
    }
}

// fused: h = relu(ax @ W1 + b1)  (64)  ->  hml = h @ [W_mu | W_logstd]  (32)
// thread-per-node; weights staged in LDS (broadcast reads).
__global__ void k_layer1(const float* __restrict__ ax, const float* __restrict__ W1,
                         const float* __restrict__ b1, const float* __restrict__ W_mu,
                         const float* __restrict__ W_logstd, float* __restrict__ hml, int N) {
    __shared__ float W1s[2 * HID];
    __shared__ float b1s[HID];
    __shared__ float Wcs[HID * 32];
    for (int t = threadIdx.x; t < 2 * HID; t += blockDim.x) W1s[t] = W1[t];
    for (int t = threadIdx.x; t < HID; t += blockDim.x) b1s[t] = b1[t];
    for (int t = threadIdx.x; t < HID * 32; t += blockDim.x) {
        int k = t >> 5, c = t & 31;
        Wcs[t] = (c < OUTC) ? W_mu[k * OUTC + c] : W_logstd[k * OUTC + (c - OUTC)];
    }
    __syncthreads();
    int n = blockIdx.x * blockDim.x + threadIdx.x;
    if (n >= N) return;
    float2 a = ((const float2*)ax)[n];
    float acc[32];
#pragma unroll
    for (int c = 0; c < 32; ++c) acc[c] = 0.0f;
#pragma unroll
    for (int k = 0; k < HID; ++k) {
        float hk = fmaxf(fmaf(a.x, W1s[k], fmaf(a.y, W1s[HID + k], b1s[k])), 0.0f);
#pragma unroll
        for (int c = 0; c < 32; ++c) acc[c] = fmaf(hk, Wcs[k * 32 + c], acc[c]);
    }
    float4* o = (float4*)(hml + (size_t)n * 32);
#pragma unroll
    for (int q = 0; q < 8; ++q)
        o[q] = make_float4(acc[4 * q], acc[4 * q + 1], acc[4 * q + 2], acc[4 * q + 3]);
}

// layer-2 aggregation: 8 lanes/node, float4 per lane (32 channels = 8 x float4)
__global__ void k_agg2(const float* __restrict__ hml, const int* __restrict__ row_ptr,
                       const int* __restrict__ sorted_src, const float* __restrict__ dis,
                       const float* __restrict__ b_mu, const float* __restrict__ b_logstd,
                       float* __restrict__ out, int N) {
    const float4* hml4 = (const float4*)hml;
    int node = blockIdx.x * (blockDim.x >> 3) + (threadIdx.x >> 3);
    int q = threadIdx.x & 7;
    if (node >= N) return;
    float di = dis[node];
    float4 v = hml4[(size_t)node * 8 + q];
    float s2 = di * di;
    float4 acc = make_float4(s2 * v.x, s2 * v.y, s2 * v.z, s2 * v.w);
    int beg = row_ptr[node], end = row_ptr[node + 1];
    for (int k = beg; k < end; ++k) {
        int s = sorted_src[k];
        float w = dis[s] * di;
        float4 u = hml4[(size_t)s * 8 + q];
        acc.x = fmaf(w, u.x, acc.x);
        acc.y = fmaf(w, u.y, acc.y);
        acc.z = fmaf(w, u.z, acc.z);
        acc.w = fmaf(w, u.w, acc.w);
    }
    float4 bias;
    float* dest;
    if (q < 4) {
        bias = ((const float4*)b_mu)[q];
        dest = out + (size_t)node * OUTC + 4 * q;
    } else {
        bias = ((const float4*)b_logstd)[q - 4];
        dest = out + ((size_t)N + node) * OUTC + 4 * (q - 4);
    }
    acc.x += bias.x; acc.y += bias.y; acc.z += bias.z; acc.w += bias.w;
    *(float4*)dest = acc;
}

extern "C" void kernel_launch(void* const* d_in, const int* in_sizes, int n_in,
                              void* d_out, int out_size, void* d_ws, size_t ws_size,
                              hipStream_t stream) {
    const float* x        = (const float*)d_in[0];
    const int*   eidx     = (const int*)d_in[1];
    const float* W1       = (const float*)d_in[2];
    const float* b1       = (const float*)d_in[3];
    const float* W_mu     = (const float*)d_in[4];
    const float* b_mu     = (const float*)d_in[5];
    const float* W_logstd = (const float*)d_in[6];
    const float* b_logstd = (const float*)d_in[7];
    float* out = (float*)d_out;

    const int N = in_sizes[0] / 2;       // 100000
    const int E = in_sizes[1] / 2;       // 1600000
    const int NCHUNK = (N + 1023) / 1024;

    const int* src = eidx;
    const int* dst = eidx + E;

    // workspace layout (256B-aligned segments)
    char* w = (char*)d_ws;
    auto alloc = [&](size_t bytes) -> void* {
        void* p = (void*)w;
        w += (bytes + 255) & ~(size_t)255;
        return p;
    };
    float* dis        = (float*)alloc((size_t)N * 4);
    int*   count      = (int*)  alloc((size_t)N * 4);
    int*   row_ptr    = (int*)  alloc((size_t)(N + 1) * 4);
    int*   cursor     = (int*)  alloc((size_t)N * 4);
    int*   chunk_sum  = (int*)  alloc((size_t)NCHUNK * 4);
    int*   chunk_base = (int*)  alloc((size_t)NCHUNK * 4);
    int*   sorted_src = (int*)  alloc((size_t)E * 4);
    float* ax         = (float*)alloc((size_t)N * 2 * 4);
    float* hml        = (float*)alloc((size_t)N * 32 * 4);

    hipMemsetAsync(count, 0, (size_t)N * sizeof(int), stream);

    k_count      <<<2048, 256, 0, stream>>>(dst, count, E);
    k_chunksum   <<<NCHUNK, 256, 0, stream>>>(count, chunk_sum, N);
    k_chunkscan  <<<1, 128, 0, stream>>>(chunk_sum, chunk_base, row_ptr, NCHUNK, N);
    k_nodescan   <<<NCHUNK, 1024, 0, stream>>>(count, chunk_base, x, row_ptr, cursor, dis, ax, N);
    k_scatter_agg<<<2048, 256, 0, stream>>>(src, dst, x, dis, cursor, sorted_src, ax, E);
    k_layer1     <<<(N + 255) / 256, 256, 0, stream>>>(ax, W1, b1, W_mu, W_logstd, hml, N);
    k_agg2       <<<(N + 31) / 32, 256, 0, stream>>>(hml, row_ptr, sorted_src, dis, b_mu, b_logstd, out, N);
}

// Round 4
// 420.665 us; speedup vs baseline: 1.3463x; 1.0457x over previous
//
#include <hip/hip_runtime.h>
#include <math.h>

// VGAE Encoder on MI355X.
// R4 design: two-level binned CSR build (391 coarse buckets -> per-bucket
// workgroup sort) to avoid the 100K-line random-write frontier that cost
// 207MB of HBM writes in R3. Layer-1 aggregation done in 2-channel x-domain
// (A(XW)=(AX)W), fused with the dense 2->64->32 MLP. Layer-2 aggregation
// split into 4 sequential channel-quarter passes so each 3.2MB gather table
// is per-XCD-L2 resident.

#define HID   64
#define NPB   256      // nodes per bucket (power of two: bucket = dst >> 8)
#define CAPB  5120     // per-bucket edge capacity (mean 4092 for E=1.6M, +16 sigma)
#define CPAD  16       // cursor padding in ints (64B) to spread atomic lines

// ---------- pass A: bin edges into coarse buckets ----------
__global__ void k_binfill(const int* __restrict__ src, const int* __restrict__ dst,
                          int* __restrict__ bcur, unsigned long long* __restrict__ pairs,
                          int E) {
    int i = blockIdx.x * blockDim.x + threadIdx.x;
    int stride = gridDim.x * blockDim.x;
    for (; i < E; i += stride) {
        int d = dst[i], s = src[i];
        int b = d >> 8;
        int p = atomicAdd(&bcur[b * CPAD], 1);
        pairs[(size_t)b * CAPB + p] = ((unsigned long long)d << 32) | (unsigned)s;
    }
}

// ---------- pass B: per-bucket local counting sort -> CSR ----------
__global__ void k_bucket(const unsigned long long* __restrict__ pairs,
                         const int* __restrict__ bcur,
                         int* __restrict__ row_beg, int* __restrict__ row_end,
                         float* __restrict__ dis, int* __restrict__ sorted_src, int N) {
    __shared__ int cnt[NPB];
    __shared__ int scanbuf[NPB];
    __shared__ int cur[NPB];
    int b = blockIdx.x;
    int tid = threadIdx.x;
    int nlo = b << 8;
    int size = bcur[b * CPAD];
    size_t ebase = (size_t)b * CAPB;

    cnt[tid] = 0;
    __syncthreads();
    for (int e = tid; e < size; e += NPB) {
        unsigned long long pr = pairs[ebase + e];
        int local = (int)(pr >> 32) & (NPB - 1);
        atomicAdd(&cnt[local], 1);
    }
    __syncthreads();
    // inclusive scan over NPB==blockDim
    int v = cnt[tid];
    scanbuf[tid] = v;
    __syncthreads();
    for (int off = 1; off < NPB; off <<= 1) {
        int a = (tid >= off) ? scanbuf[tid - off] : 0;
        __syncthreads();
        scanbuf[tid] += a;
        __syncthreads();
    }
    int incl = scanbuf[tid];
    int excl = incl - v;
    int n = nlo + tid;
    int gbeg = (int)ebase + excl;
    if (n < N) {
        row_beg[n] = gbeg;
        row_end[n] = (int)ebase + incl;
        dis[n] = rsqrtf(1.0f + (float)v);
    }
    cur[tid] = gbeg;
    __syncthreads();
    for (int e = tid; e < size; e += NPB) {
        unsigned long long pr = pairs[ebase + e];
        int local = (int)(pr >> 32) & (NPB - 1);
        int slot = atomicAdd(&cur[local], 1);
        sorted_src[slot] = (int)(unsigned)pr;
    }
}

// ---------- fused: ax = A_norm x (gather-side), h=relu(ax W1+b1), hml=h[Wmu|Wls] ----------
// hml stored as 4 quarter arrays [N][8] so each layer-2 gather table is 3.2MB.
__global__ void k_ax_layer1(const float* __restrict__ x, const int* __restrict__ row_beg,
                            const int* __restrict__ row_end, const int* __restrict__ sorted_src,
                            const float* __restrict__ dis,
                            const float* __restrict__ W1, const float* __restrict__ b1,
                            const float* __restrict__ W_mu, const float* __restrict__ W_logstd,
                            float* __restrict__ hml0, float* __restrict__ hml1,
                            float* __restrict__ hml2, float* __restrict__ hml3, int N) {
    __shared__ float W1s[2 * HID];
    __shared__ float b1s[HID];
    __shared__ float Wcs[HID * 32];
    for (int t = threadIdx.x; t < 2 * HID; t += blockDim.x) W1s[t] = W1[t];
    for (int t = threadIdx.x; t < HID; t += blockDim.x) b1s[t] = b1[t];
    for (int t = threadIdx.x; t < HID * 32; t += blockDim.x) {
        int k = t >> 5, c = t & 31;
        Wcs[t] = (c < 16) ? W_mu[k * 16 + c] : W_logstd[k * 16 + (c - 16)];
    }
    __syncthreads();
    int gid = blockIdx.x * blockDim.x + threadIdx.x;
    int stride = gridDim.x * blockDim.x;
    const float2* x2 = (const float2*)x;
    for (int n = gid; n < N; n += stride) {
        float di = dis[n];
        float2 xv = x2[n];
        float axx = di * di * xv.x, axy = di * di * xv.y;
        int beg = row_beg[n], end = row_end[n];
        for (int k = beg; k < end; ++k) {
            int s = sorted_src[k];
            float w = di * dis[s];
            float2 u = x2[s];
            axx = fmaf(w, u.x, axx);
            axy = fmaf(w, u.y, axy);
        }
        float acc[32];
#pragma unroll
        for (int c = 0; c < 32; ++c) acc[c] = 0.0f;
#pragma unroll
        for (int k = 0; k < HID; ++k) {
            float hk = fmaxf(fmaf(axx, W1s[k], fmaf(axy, W1s[HID + k], b1s[k])), 0.0f);
#pragma unroll
            for (int c = 0; c < 32; ++c) acc[c] = fmaf(hk, Wcs[k * 32 + c], acc[c]);
        }
        float4* o0 = (float4*)(hml0 + (size_t)n * 8);
        float4* o1 = (float4*)(hml1 + (size_t)n * 8);
        float4* o2 = (float4*)(hml2 + (size_t)n * 8);
        float4* o3 = (float4*)(hml3 + (size_t)n * 8);
        o0[0] = make_float4(acc[0], acc[1], acc[2], acc[3]);
        o0[1] = make_float4(acc[4], acc[5], acc[6], acc[7]);
        o1[0] = make_float4(acc[8], acc[9], acc[10], acc[11]);
        o1[1] = make_float4(acc[12], acc[13], acc[14], acc[15]);
        o2[0] = make_float4(acc[16], acc[17], acc[18], acc[19]);
        o2[1] = make_float4(acc[20], acc[21], acc[22], acc[23]);
        o3[0] = make_float4(acc[24], acc[25], acc[26], acc[27]);
        o3[1] = make_float4(acc[28], acc[29], acc[30], acc[31]);
    }
}

// ---------- layer-2 aggregation, one 8-channel quarter per launch ----------
// 2 lanes per node, float4 per lane. hq table is 3.2MB -> per-XCD L2 resident.
__global__ void k_agg2q(const float* __restrict__ hq, const int* __restrict__ row_beg,
                        const int* __restrict__ row_end, const int* __restrict__ sorted_src,
                        const float* __restrict__ dis, const float* __restrict__ bias,
                        float* __restrict__ outp, int coff, int N) {
    const float4* hq4 = (const float4*)hq;
    int gid = blockIdx.x * blockDim.x + threadIdx.x;
    int node = gid >> 1;
    int half = gid & 1;
    if (node >= N) return;
    float di = dis[node];
    float4 v = hq4[(size_t)node * 2 + half];
    float s2 = di * di;
    float4 acc = make_float4(s2 * v.x, s2 * v.y, s2 * v.z, s2 * v.w);
    int beg = row_beg[node], end = row_end[node];
    for (int k = beg; k < end; ++k) {
        int s = sorted_src[k];
        float w = di * dis[s];
        float4 u = hq4[(size_t)s * 2 + half];
        acc.x = fmaf(w, u.x, acc.x);
        acc.y = fmaf(w, u.y, acc.y);
        acc.z = fmaf(w, u.z, acc.z);
        acc.w = fmaf(w, u.w, acc.w);
    }
    float4 bv = *(const float4*)(bias + coff + half * 4);
    acc.x += bv.x; acc.y += bv.y; acc.z += bv.z; acc.w += bv.w;
    *(float4*)(outp + (size_t)node * 16 + coff + half * 4) = acc;
}

extern "C" void kernel_launch(void* const* d_in, const int* in_sizes, int n_in,
                              void* d_out, int out_size, void* d_ws, size_t ws_size,
                              hipStream_t stream) {
    const float* x        = (const float*)d_in[0];
    const int*   eidx     = (const int*)d_in[1];
    const float* W1       = (const float*)d_in[2];
    const float* b1       = (const float*)d_in[3];
    const float* W_mu     = (const float*)d_in[4];
    const float* b_mu     = (const float*)d_in[5];
    const float* W_logstd = (const float*)d_in[6];
    const float* b_logstd = (const float*)d_in[7];
    float* out = (float*)d_out;

    const int N = in_sizes[0] / 2;       // 100000
    const int E = in_sizes[1] / 2;       // 1600000
    const int NBUCKET = (N + NPB - 1) / NPB;   // 391

    const int* src = eidx;
    const int* dst = eidx + E;

    char* w = (char*)d_ws;
    auto alloc = [&](size_t bytes) -> void* {
        void* p = (void*)w;
        w += (bytes + 255) & ~(size_t)255;
        return p;
    };
    int* bcur = (int*)alloc((size_t)NBUCKET * CPAD * 4);
    unsigned long long* pairs = (unsigned long long*)alloc((size_t)NBUCKET * CAPB * 8);
    int*   sorted_src = (int*)  alloc((size_t)NBUCKET * CAPB * 4);
    int*   row_beg    = (int*)  alloc((size_t)N * 4);
    int*   row_end    = (int*)  alloc((size_t)N * 4);
    float* dis        = (float*)alloc((size_t)N * 4);
    float* hml0       = (float*)alloc((size_t)N * 8 * 4);
    float* hml1       = (float*)alloc((size_t)N * 8 * 4);
    float* hml2       = (float*)alloc((size_t)N * 8 * 4);
    float* hml3       = (float*)alloc((size_t)N * 8 * 4);

    hipMemsetAsync(bcur, 0, (size_t)NBUCKET * CPAD * 4, stream);

    k_binfill<<<2048, 256, 0, stream>>>(src, dst, bcur, pairs, E);
    k_bucket <<<NBUCKET, NPB, 0, stream>>>(pairs, bcur, row_beg, row_end, dis, sorted_src, N);
    k_ax_layer1<<<(N + 255) / 256, 256, 0, stream>>>(x, row_beg, row_end, sorted_src, dis,
                                                     W1, b1, W_mu, W_logstd,
                                                     hml0, hml1, hml2, hml3, N);
    int agg_wgs = (2 * N + 255) / 256;
    // sequential passes: each quarter table stays L2-resident
    k_agg2q<<<agg_wgs, 256, 0, stream>>>(hml0, row_beg, row_end, sorted_src, dis, b_mu,      out,                 0, N);
    k_agg2q<<<agg_wgs, 256, 0, stream>>>(hml1, row_beg, row_end, sorted_src, dis, b_mu,      out,                 8, N);
    k_agg2q<<<agg_wgs, 256, 0, stream>>>(hml2, row_beg, row_end, sorted_src, dis, b_logstd,  out + (size_t)N * 16, 0, N);
    k_agg2q<<<agg_wgs, 256, 0, stream>>>(hml3, row_beg, row_end, sorted_src, dis, b_logstd,  out + (size_t)N * 16, 8, N);
}

// Round 5
// 356.778 us; speedup vs baseline: 1.5874x; 1.1791x over previous
//
#include <hip/hip_runtime.h>
#include <math.h>

// VGAE Encoder on MI355X — R5.
// Binned CSR (1563 buckets of 64 nodes, wave-per-bucket counting sort with
// LDS-staged coalesced output), 32-lane-per-node fused gather+MLP, and a
// single XCD-partitioned layer-2 aggregation over four 3.2MB L2-resident
// channel-quarter tables.

#define CAPB  1280     // per-bucket edge capacity (mean 1024, +8 sigma)
#define CPAD  16       // cursor padding in ints (64B)

// ---------- pass A: bin edges into 64-node buckets ----------
__global__ void k_binfill(const int* __restrict__ src, const int* __restrict__ dst,
                          int* __restrict__ bcur, unsigned* __restrict__ pairs, int E) {
    int i = blockIdx.x * blockDim.x + threadIdx.x;
    int stride = gridDim.x * blockDim.x;
    for (; i < E; i += stride) {
        int d = dst[i];
        unsigned s = (unsigned)src[i];
        int b = d >> 6;
        int p = atomicAdd(&bcur[b * CPAD], 1);
        pairs[b * CAPB + p] = ((unsigned)(d & 63) << 20) | s;   // src < 2^20
    }
}

// ---------- pass B: wave-per-bucket counting sort (no __syncthreads) ----------
__global__ void k_bucket(const unsigned* __restrict__ pairs, const int* __restrict__ bcur,
                         int* __restrict__ row_beg, int* __restrict__ row_end,
                         float* __restrict__ dis, int* __restrict__ sorted_src,
                         int nbucket, int N) {
    __shared__ int hist[4][64];
    __shared__ int lbuf[4][CAPB];
    int w = threadIdx.x >> 6, lane = threadIdx.x & 63;
    int b = blockIdx.x * 4 + w;
    if (b >= nbucket) return;
    int size = bcur[b * CPAD];
    int ebase = b * CAPB;

    hist[w][lane] = 0;
    for (int e = lane; e < size; e += 64) {
        unsigned pr = pairs[ebase + e];
        atomicAdd(&hist[w][pr >> 20], 1);
    }
    int v = hist[w][lane];
    int incl = v;
    for (int off = 1; off < 64; off <<= 1) {
        int a = __shfl_up(incl, off, 64);
        if (lane >= off) incl += a;
    }
    int excl = incl - v;
    int n = (b << 6) + lane;
    if (n < N) {
        row_beg[n] = ebase + excl;
        row_end[n] = ebase + incl;
        dis[n] = rsqrtf(1.0f + (float)v);
    }
    hist[w][lane] = excl;                       // local cursor
    for (int e = lane; e < size; e += 64) {
        unsigned pr = pairs[ebase + e];
        int slot = atomicAdd(&hist[w][pr >> 20], 1);
        lbuf[w][slot] = (int)(pr & 0xFFFFFu);
    }
    for (int e = lane; e < size; e += 64)       // coalesced drain
        sorted_src[ebase + e] = lbuf[w][e];
}

// ---------- fused gather + dense MLP: 32 lanes per node ----------
// ax = A_norm x (2ch); h = relu(ax W1 + b1) (64); hml = h [W_mu|W_logstd] (32)
// stored as 4 quarter tables [N][8] (3.2MB each).
__global__ void k_mlp(const float* __restrict__ x, const int* __restrict__ row_beg,
                      const int* __restrict__ row_end, const int* __restrict__ sorted_src,
                      const float* __restrict__ dis,
                      const float* __restrict__ W1, const float* __restrict__ b1,
                      const float* __restrict__ W_mu, const float* __restrict__ W_logstd,
                      float* __restrict__ hml0, float* __restrict__ hml1,
                      float* __restrict__ hml2, float* __restrict__ hml3, int N) {
    __shared__ float W1s[128];
    __shared__ float b1s[64];
    __shared__ float Wcs[64 * 32];
    for (int t = threadIdx.x; t < 128; t += 256) W1s[t] = W1[t];
    for (int t = threadIdx.x; t < 64; t += 256) b1s[t] = b1[t];
    for (int t = threadIdx.x; t < 2048; t += 256) {
        int k = t >> 5, c = t & 31;
        Wcs[t] = (c < 16) ? W_mu[k * 16 + c] : W_logstd[k * 16 + (c - 16)];
    }
    __syncthreads();
    int node = blockIdx.x * 8 + (threadIdx.x >> 5);
    int c = threadIdx.x & 31;
    if (node >= N) return;
    const float2* x2 = (const float2*)x;
    float di = dis[node];
    int beg = row_beg[node], end = row_end[node];
    float axx = 0.0f, axy = 0.0f;
    for (int e = beg + c; e < end; e += 32) {
        int s = sorted_src[e];
        float w = di * dis[s];
        float2 u = x2[s];
        axx = fmaf(w, u.x, axx);
        axy = fmaf(w, u.y, axy);
    }
#pragma unroll
    for (int off = 16; off; off >>= 1) {
        axx += __shfl_xor(axx, off, 32);
        axy += __shfl_xor(axy, off, 32);
    }
    float2 xv = x2[node];
    axx = fmaf(di * di, xv.x, axx);
    axy = fmaf(di * di, xv.y, axy);
    // hk for k = c and k = c+32
    float h0 = fmaxf(fmaf(axx, W1s[c],      fmaf(axy, W1s[64 + c],  b1s[c])),      0.0f);
    float h1 = fmaxf(fmaf(axx, W1s[32 + c], fmaf(axy, W1s[96 + c],  b1s[32 + c])), 0.0f);
    float acc = 0.0f;
#pragma unroll
    for (int k = 0; k < 32; ++k) {
        float hk = __shfl(h0, k, 32);
        acc = fmaf(hk, Wcs[k * 32 + c], acc);
    }
#pragma unroll
    for (int k = 0; k < 32; ++k) {
        float hk = __shfl(h1, k, 32);
        acc = fmaf(hk, Wcs[(k + 32) * 32 + c], acc);
    }
    float* hq = (c < 8) ? hml0 : (c < 16) ? hml1 : (c < 24) ? hml2 : hml3;
    hq[(size_t)node * 8 + (c & 7)] = acc;
}

// ---------- layer-2 aggregation: 4 quarters, XCD-partitioned, one launch ----------
// quarter q = (blockIdx%8)>>1 -> blocks of quarter q land on XCDs {2q,2q+1}
// (round-robin heuristic); each 3.2MB table stays in 2 XCDs' L2.
__global__ void k_agg2(const float* __restrict__ hml0, const float* __restrict__ hml1,
                       const float* __restrict__ hml2, const float* __restrict__ hml3,
                       const int* __restrict__ row_beg, const int* __restrict__ row_end,
                       const int* __restrict__ sorted_src, const float* __restrict__ dis,
                       const float* __restrict__ b_mu, const float* __restrict__ b_logstd,
                       float* __restrict__ out, int N) {
    int b = blockIdx.x;
    int q = (b & 7) >> 1;
    int sub = ((b >> 3) << 1) | (b & 1);
    int gid = sub * 256 + threadIdx.x;
    int node = gid >> 1, half = gid & 1;
    if (node >= N) return;
    const float4* h4 = (const float4*)(q == 0 ? hml0 : q == 1 ? hml1 : q == 2 ? hml2 : hml3);
    float di = dis[node];
    float4 v = h4[(size_t)node * 2 + half];
    float s2 = di * di;
    float4 acc = make_float4(s2 * v.x, s2 * v.y, s2 * v.z, s2 * v.w);
    int beg = row_beg[node], end = row_end[node];
    for (int k = beg; k < end; ++k) {
        int s = sorted_src[k];
        float w = di * dis[s];
        float4 u = h4[(size_t)s * 2 + half];
        acc.x = fmaf(w, u.x, acc.x);
        acc.y = fmaf(w, u.y, acc.y);
        acc.z = fmaf(w, u.z, acc.z);
        acc.w = fmaf(w, u.w, acc.w);
    }
    const float* bp = (q < 2 ? b_mu : b_logstd) + ((q & 1) << 3) + (half << 2);
    float4 bv = *(const float4*)bp;
    acc.x += bv.x; acc.y += bv.y; acc.z += bv.z; acc.w += bv.w;
    float* op = out + ((q < 2 ? (size_t)0 : (size_t)N) + node) * 16 + ((q & 1) << 3) + (half << 2);
    *(float4*)op = acc;
}

extern "C" void kernel_launch(void* const* d_in, const int* in_sizes, int n_in,
                              void* d_out, int out_size, void* d_ws, size_t ws_size,
                              hipStream_t stream) {
    const float* x        = (const float*)d_in[0];
    const int*   eidx     = (const int*)d_in[1];
    const float* W1       = (const float*)d_in[2];
    const float* b1       = (const float*)d_in[3];
    const float* W_mu     = (const float*)d_in[4];
    const float* b_mu     = (const float*)d_in[5];
    const float* W_logstd = (const float*)d_in[6];
    const float* b_logstd = (const float*)d_in[7];
    float* out = (float*)d_out;

    const int N = in_sizes[0] / 2;            // 100000
    const int E = in_sizes[1] / 2;            // 1600000
    const int NBUCKET = (N + 63) >> 6;        // 1563

    const int* src = eidx;
    const int* dst = eidx + E;

    char* w = (char*)d_ws;
    auto alloc = [&](size_t bytes) -> void* {
        void* p = (void*)w;
        w += (bytes + 255) & ~(size_t)255;
        return p;
    };
    int*      bcur       = (int*)     alloc((size_t)NBUCKET * CPAD * 4);
    unsigned* pairs      = (unsigned*)alloc((size_t)NBUCKET * CAPB * 4);
    int*      sorted_src = (int*)     alloc((size_t)NBUCKET * CAPB * 4);
    int*      row_beg    = (int*)     alloc((size_t)N * 4);
    int*      row_end    = (int*)     alloc((size_t)N * 4);
    float*    dis        = (float*)   alloc((size_t)N * 4);
    float*    hml0       = (float*)   alloc((size_t)N * 8 * 4);
    float*    hml1       = (float*)   alloc((size_t)N * 8 * 4);
    float*    hml2       = (float*)   alloc((size_t)N * 8 * 4);
    float*    hml3       = (float*)   alloc((size_t)N * 8 * 4);

    hipMemsetAsync(bcur, 0, (size_t)NBUCKET * CPAD * 4, stream);

    k_binfill<<<2048, 256, 0, stream>>>(src, dst, bcur, pairs, E);
    k_bucket <<<(NBUCKET + 3) / 4, 256, 0, stream>>>(pairs, bcur, row_beg, row_end, dis,
                                                     sorted_src, NBUCKET, N);
    k_mlp    <<<(N + 7) / 8, 256, 0, stream>>>(x, row_beg, row_end, sorted_src, dis,
                                               W1, b1, W_mu, W_logstd,
                                               hml0, hml1, hml2, hml3, N);
    int qblocks = (2 * N + 255) / 256;        // 782 per quarter
    k_agg2   <<<((qblocks + 1) / 2) * 8, 256, 0, stream>>>(hml0, hml1, hml2, hml3,
                                                           row_beg, row_end, sorted_src, dis,
                                                           b_mu, b_logstd, out, N);
}

// Round 6
// 320.012 us; speedup vs baseline: 1.7698x; 1.1149x over previous
//
#include <hip/hip_runtime.h>
#include <math.h>

// VGAE Encoder on MI355X — R6.
// R5 found: binfill's 4B scatters into 1563 bucket regions written from all
// 8 XCDs -> 13x partial-line writeback amplification (82MB for 6.4MB payload).
// R6: slice every bucket 8-way by (blockIdx&7) ~ XCD id (dispatch round-robin),
// slice-major layout, so each append region + its cursor line is written by
// ONE XCD's L2 -> full-line writebacks. k_bucket concatenates the 8 slices.

#define CAPB  1280     // per-bucket total edge capacity (mean 1024, +8 sigma)
#define SCAP  224      // per-slice capacity (mean 128, +8.5 sigma)
#define NSL   8        // slices (XCDs)

// ---------- pass A: bin edges into (slice, bucket) sub-regions ----------
__global__ void k_binfill(const int* __restrict__ src, const int* __restrict__ dst,
                          int* __restrict__ bcur, unsigned* __restrict__ pairs,
                          int E, int nbucket) {
    int sl = blockIdx.x & (NSL - 1);               // heuristic XCD id
    int* cur = bcur + sl * nbucket;
    unsigned* pp = pairs + (size_t)sl * nbucket * SCAP;
    int i = blockIdx.x * blockDim.x + threadIdx.x;
    int stride = gridDim.x * blockDim.x;
    for (; i < E; i += stride) {
        int d = dst[i];
        unsigned s = (unsigned)src[i];
        int b = d >> 6;
        int p = atomicAdd(&cur[b], 1);
        pp[b * SCAP + p] = ((unsigned)(d & 63) << 20) | s;   // src < 2^20
    }
}

// ---------- pass B: wave-per-bucket counting sort over 8 slices ----------
__global__ void k_bucket(const unsigned* __restrict__ pairs, const int* __restrict__ bcur,
                         int* __restrict__ row_beg, int* __restrict__ row_end,
                         float* __restrict__ dis, int* __restrict__ sorted_src,
                         int nbucket, int N) {
    __shared__ int hist[4][64];
    __shared__ int lbuf[4][CAPB];
    int w = threadIdx.x >> 6, lane = threadIdx.x & 63;
    int b = blockIdx.x * 4 + w;
    if (b >= nbucket) return;
    int ebase = b * CAPB;

    hist[w][lane] = 0;
    for (int sl = 0; sl < NSL; ++sl) {
        int size = bcur[sl * nbucket + b];
        const unsigned* pp = pairs + ((size_t)sl * nbucket + b) * SCAP;
        for (int e = lane; e < size; e += 64)
            atomicAdd(&hist[w][pp[e] >> 20], 1);
    }
    int v = hist[w][lane];
    int incl = v;
    for (int off = 1; off < 64; off <<= 1) {
        int a = __shfl_up(incl, off, 64);
        if (lane >= off) incl += a;
    }
    int excl = incl - v;
    int n = (b << 6) + lane;
    if (n < N) {
        row_beg[n] = ebase + excl;
        row_end[n] = ebase + incl;
        dis[n] = rsqrtf(1.0f + (float)v);
    }
    hist[w][lane] = excl;                       // local cursor
    int tot = __shfl(incl, 63, 64);             // bucket total
    for (int sl = 0; sl < NSL; ++sl) {
        int size = bcur[sl * nbucket + b];
        const unsigned* pp = pairs + ((size_t)sl * nbucket + b) * SCAP;
        for (int e = lane; e < size; e += 64) {
            unsigned pr = pp[e];
            int slot = atomicAdd(&hist[w][pr >> 20], 1);
            lbuf[w][slot] = (int)(pr & 0xFFFFFu);
        }
    }
    for (int e = lane; e < tot; e += 64)        // coalesced drain
        sorted_src[ebase + e] = lbuf[w][e];
}

// ---------- fused gather + dense MLP: 32 lanes per node ----------
__global__ void k_mlp(const float* __restrict__ x, const int* __restrict__ row_beg,
                      const int* __restrict__ row_end, const int* __restrict__ sorted_src,
                      const float* __restrict__ dis,
                      const float* __restrict__ W1, const float* __restrict__ b1,
                      const float* __restrict__ W_mu, const float* __restrict__ W_logstd,
                      float* __restrict__ hml0, float* __restrict__ hml1,
                      float* __restrict__ hml2, float* __restrict__ hml3, int N) {
    __shared__ float W1s[128];
    __shared__ float b1s[64];
    __shared__ float Wcs[64 * 32];
    for (int t = threadIdx.x; t < 128; t += 256) W1s[t] = W1[t];
    for (int t = threadIdx.x; t < 64; t += 256) b1s[t] = b1[t];
    for (int t = threadIdx.x; t < 2048; t += 256) {
        int k = t >> 5, c = t & 31;
        Wcs[t] = (c < 16) ? W_mu[k * 16 + c] : W_logstd[k * 16 + (c - 16)];
    }
    __syncthreads();
    int node = blockIdx.x * 8 + (threadIdx.x >> 5);
    int c = threadIdx.x & 31;
    if (node >= N) return;
    const float2* x2 = (const float2*)x;
    float di = dis[node];
    int beg = row_beg[node], end = row_end[node];
    float axx = 0.0f, axy = 0.0f;
    for (int e = beg + c; e < end; e += 32) {
        int s = sorted_src[e];
        float w = di * dis[s];
        float2 u = x2[s];
        axx = fmaf(w, u.x, axx);
        axy = fmaf(w, u.y, axy);
    }
#pragma unroll
    for (int off = 16; off; off >>= 1) {
        axx += __shfl_xor(axx, off, 32);
        axy += __shfl_xor(axy, off, 32);
    }
    float2 xv = x2[node];
    axx = fmaf(di * di, xv.x, axx);
    axy = fmaf(di * di, xv.y, axy);
    float h0 = fmaxf(fmaf(axx, W1s[c],      fmaf(axy, W1s[64 + c],  b1s[c])),      0.0f);
    float h1 = fmaxf(fmaf(axx, W1s[32 + c], fmaf(axy, W1s[96 + c],  b1s[32 + c])), 0.0f);
    float acc = 0.0f;
#pragma unroll
    for (int k = 0; k < 32; ++k) {
        float hk = __shfl(h0, k, 32);
        acc = fmaf(hk, Wcs[k * 32 + c], acc);
    }
#pragma unroll
    for (int k = 0; k < 32; ++k) {
        float hk = __shfl(h1, k, 32);
        acc = fmaf(hk, Wcs[(k + 32) * 32 + c], acc);
    }
    float* hq = (c < 8) ? hml0 : (c < 16) ? hml1 : (c < 24) ? hml2 : hml3;
    hq[(size_t)node * 8 + (c & 7)] = acc;
}

// ---------- layer-2 aggregation: 4 quarters, XCD-partitioned, one launch ----------
__global__ void k_agg2(const float* __restrict__ hml0, const float* __restrict__ hml1,
                       const float* __restrict__ hml2, const float* __restrict__ hml3,
                       const int* __restrict__ row_beg, const int* __restrict__ row_end,
                       const int* __restrict__ sorted_src, const float* __restrict__ dis,
                       const float* __restrict__ b_mu, const float* __restrict__ b_logstd,
                       float* __restrict__ out, int N) {
    int b = blockIdx.x;
    int q = (b & 7) >> 1;
    int sub = ((b >> 3) << 1) | (b & 1);
    int gid = sub * 256 + threadIdx.x;
    int node = gid >> 1, half = gid & 1;
    if (node >= N) return;
    const float4* h4 = (const float4*)(q == 0 ? hml0 : q == 1 ? hml1 : q == 2 ? hml2 : hml3);
    float di = dis[node];
    float4 v = h4[(size_t)node * 2 + half];
    float s2 = di * di;
    float4 acc = make_float4(s2 * v.x, s2 * v.y, s2 * v.z, s2 * v.w);
    int beg = row_beg[node], end = row_end[node];
    for (int k = beg; k < end; ++k) {
        int s = sorted_src[k];
        float w = di * dis[s];
        float4 u = h4[(size_t)s * 2 + half];
        acc.x = fmaf(w, u.x, acc.x);
        acc.y = fmaf(w, u.y, acc.y);
        acc.z = fmaf(w, u.z, acc.z);
        acc.w = fmaf(w, u.w, acc.w);
    }
    const float* bp = (q < 2 ? b_mu : b_logstd) + ((q & 1) << 3) + (half << 2);
    float4 bv = *(const float4*)bp;
    acc.x += bv.x; acc.y += bv.y; acc.z += bv.z; acc.w += bv.w;
    float* op = out + ((q < 2 ? (size_t)0 : (size_t)N) + node) * 16 + ((q & 1) << 3) + (half << 2);
    *(float4*)op = acc;
}

extern "C" void kernel_launch(void* const* d_in, const int* in_sizes, int n_in,
                              void* d_out, int out_size, void* d_ws, size_t ws_size,
                              hipStream_t stream) {
    const float* x        = (const float*)d_in[0];
    const int*   eidx     = (const int*)d_in[1];
    const float* W1       = (const float*)d_in[2];
    const float* b1       = (const float*)d_in[3];
    const float* W_mu     = (const float*)d_in[4];
    const float* b_mu     = (const float*)d_in[5];
    const float* W_logstd = (const float*)d_in[6];
    const float* b_logstd = (const float*)d_in[7];
    float* out = (float*)d_out;

    const int N = in_sizes[0] / 2;            // 100000
    const int E = in_sizes[1] / 2;            // 1600000
    const int NBUCKET = (N + 63) >> 6;        // 1563

    const int* src = eidx;
    const int* dst = eidx + E;

    char* w = (char*)d_ws;
    auto alloc = [&](size_t bytes) -> void* {
        void* p = (void*)w;
        w += (bytes + 255) & ~(size_t)255;
        return p;
    };
    int*      bcur       = (int*)     alloc((size_t)NSL * NBUCKET * 4);
    unsigned* pairs      = (unsigned*)alloc((size_t)NSL * NBUCKET * SCAP * 4);
    int*      sorted_src = (int*)     alloc((size_t)NBUCKET * CAPB * 4);
    int*      row_beg    = (int*)     alloc((size_t)N * 4);
    int*      row_end    = (int*)     alloc((size_t)N * 4);
    float*    dis        = (float*)   alloc((size_t)N * 4);
    float*    hml0       = (float*)   alloc((size_t)N * 8 * 4);
    float*    hml1       = (float*)   alloc((size_t)N * 8 * 4);
    float*    hml2       = (float*)   alloc((size_t)N * 8 * 4);
    float*    hml3       = (float*)   alloc((size_t)N * 8 * 4);

    hipMemsetAsync(bcur, 0, (size_t)NSL * NBUCKET * 4, stream);

    k_binfill<<<2048, 256, 0, stream>>>(src, dst, bcur, pairs, E, NBUCKET);
    k_bucket <<<(NBUCKET + 3) / 4, 256, 0, stream>>>(pairs, bcur, row_beg, row_end, dis,
                                                     sorted_src, NBUCKET, N);
    k_mlp    <<<(N + 7) / 8, 256, 0, stream>>>(x, row_beg, row_end, sorted_src, dis,
                                               W1, b1, W_mu, W_logstd,
                                               hml0, hml1, hml2, hml3, N);
    int qblocks = (2 * N + 255) / 256;
    k_agg2   <<<((qblocks + 1) / 2) * 8, 256, 0, stream>>>(hml0, hml1, hml2, hml3,
                                                           row_beg, row_end, sorted_src, dis,
                                                           b_mu, b_logstd, out, N);
}